// Round 1
// baseline (359.209 us; speedup 1.0000x reference)
//
#include <hip/hip_runtime.h>

// MaskedPooling: out[b,d] = sum_t x[b,t,d]*keep[b,t] / sum_t keep[b,t]
// x: [B=32, T=4096, D=512] fp32; mask: [B,T] int (nonzero = excluded)

#define BB 32
#define TT 4096
#define DD 512
#define SPLITS 32
#define ROWS_PER_BLOCK (TT / SPLITS)   // 128 rows per block
#define WS_FLOATS ((size_t)BB * SPLITS * DD)  // 2 MiB of partials

// ---------------- primary path: two-stage, no atomics ----------------

__global__ __launch_bounds__(256) void masked_pool_partial_ws(
    const float* __restrict__ x, const int* __restrict__ mask,
    float4* __restrict__ ws)
{
    __shared__ float  s_keep[ROWS_PER_BLOCK];
    __shared__ float4 s_acc[DD / 4];      // 2 KiB, combine the two row-groups

    const int b   = blockIdx.x;
    const int s   = blockIdx.y;
    const int tid = threadIdx.x;
    const int t0  = s * ROWS_PER_BLOCK;

    if (tid < ROWS_PER_BLOCK) {
        s_keep[tid] = (mask[b * TT + t0 + tid] == 0) ? 1.0f : 0.0f;
    }
    __syncthreads();

    const int tx = tid & 127;   // float4 column: covers D=512 floats
    const int ty = tid >> 7;    // 0..1 row-group

    const float4* xrow = (const float4*)(x + (size_t)b * TT * DD)
                         + (size_t)t0 * (DD / 4);

    float4 acc = make_float4(0.f, 0.f, 0.f, 0.f);
    #pragma unroll 8
    for (int r = ty; r < ROWS_PER_BLOCK; r += 2) {
        float  k = s_keep[r];                         // LDS broadcast
        float4 v = xrow[(size_t)r * (DD / 4) + tx];   // coalesced 16B/lane
        acc.x += k * v.x;
        acc.y += k * v.y;
        acc.z += k * v.z;
        acc.w += k * v.w;
    }

    if (ty == 1) s_acc[tx] = acc;
    __syncthreads();
    if (ty == 0) {
        float4 o = s_acc[tx];
        acc.x += o.x; acc.y += o.y; acc.z += o.z; acc.w += o.w;
        // ws layout: [b][s][D/4] — coalesced 2 KiB store per block
        ws[((size_t)b * SPLITS + s) * (DD / 4) + tx] = acc;
    }
}

__global__ __launch_bounds__(128) void masked_pool_reduce(
    const float4* __restrict__ ws, const int* __restrict__ mask,
    float4* __restrict__ out)
{
    const int b   = blockIdx.x;
    const int tid = threadIdx.x;

    // denom[b]: mask is L2-hot (just read by kernel 1)
    int cnt = 0;
    #pragma unroll
    for (int t = tid; t < TT; t += 128) cnt += (mask[b * TT + t] == 0) ? 1 : 0;
    #pragma unroll
    for (int off = 32; off > 0; off >>= 1) cnt += __shfl_down(cnt, off, 64);

    __shared__ int s_cnt[2];
    if ((tid & 63) == 0) s_cnt[tid >> 6] = cnt;
    __syncthreads();
    const float inv = 1.0f / (float)(s_cnt[0] + s_cnt[1]);

    // reduce the 32 partials for this b; ws is L2-resident (2 MiB)
    float4 acc = make_float4(0.f, 0.f, 0.f, 0.f);
    #pragma unroll
    for (int s = 0; s < SPLITS; ++s) {
        float4 v = ws[((size_t)b * SPLITS + s) * (DD / 4) + tid];
        acc.x += v.x; acc.y += v.y; acc.z += v.z; acc.w += v.w;
    }
    acc.x *= inv; acc.y *= inv; acc.z *= inv; acc.w *= inv;
    out[(size_t)b * (DD / 4) + tid] = acc;
}

// ---------------- fallback path (ws too small): previous atomic version ----------------

__global__ __launch_bounds__(256) void masked_pool_partial_atomic(
    const float* __restrict__ x, const int* __restrict__ mask,
    float* __restrict__ out)
{
    __shared__ float s_keep[ROWS_PER_BLOCK];
    const int b   = blockIdx.x;
    const int s   = blockIdx.y;
    const int tid = threadIdx.x;
    const int t0  = s * ROWS_PER_BLOCK;

    if (tid < ROWS_PER_BLOCK) {
        s_keep[tid] = (mask[b * TT + t0 + tid] == 0) ? 1.0f : 0.0f;
    }
    __syncthreads();

    const int tx = tid & 127;
    const int ty = tid >> 7;

    const float4* xrow = (const float4*)(x + (size_t)b * TT * DD)
                         + (size_t)t0 * (DD / 4);

    float4 acc = make_float4(0.f, 0.f, 0.f, 0.f);
    #pragma unroll 8
    for (int r = ty; r < ROWS_PER_BLOCK; r += 2) {
        float  k = s_keep[r];
        float4 v = xrow[(size_t)r * (DD / 4) + tx];
        acc.x += k * v.x;
        acc.y += k * v.y;
        acc.z += k * v.z;
        acc.w += k * v.w;
    }

    float* o = out + (size_t)b * DD + tx * 4;
    atomicAdd(o + 0, acc.x);
    atomicAdd(o + 1, acc.y);
    atomicAdd(o + 2, acc.z);
    atomicAdd(o + 3, acc.w);
}

__global__ __launch_bounds__(256) void masked_pool_scale(
    const int* __restrict__ mask, float* __restrict__ out)
{
    const int b   = blockIdx.x;
    const int tid = threadIdx.x;

    int cnt = 0;
    #pragma unroll
    for (int t = tid; t < TT; t += 256) cnt += (mask[b * TT + t] == 0) ? 1 : 0;
    #pragma unroll
    for (int off = 32; off > 0; off >>= 1) cnt += __shfl_down(cnt, off, 64);

    __shared__ int s_cnt[4];
    if ((tid & 63) == 0) s_cnt[tid >> 6] = cnt;
    __syncthreads();

    const int denom = s_cnt[0] + s_cnt[1] + s_cnt[2] + s_cnt[3];
    const float inv = 1.0f / (float)denom;

    for (int d = tid; d < DD; d += 256) out[(size_t)b * DD + d] *= inv;
}

extern "C" void kernel_launch(void* const* d_in, const int* in_sizes, int n_in,
                              void* d_out, int out_size, void* d_ws, size_t ws_size,
                              hipStream_t stream) {
    const float* x    = (const float*)d_in[0];
    const int*   mask = (const int*)d_in[1];
    float*       out  = (float*)d_out;

    if (ws_size >= WS_FLOATS * sizeof(float)) {
        // two-stage deterministic reduction through workspace — no memset, no atomics
        float4* ws = (float4*)d_ws;
        dim3 grid(BB, SPLITS);
        masked_pool_partial_ws<<<grid, 256, 0, stream>>>(x, mask, ws);
        masked_pool_reduce<<<BB, 128, 0, stream>>>(ws, mask, (float4*)out);
    } else {
        // fallback: atomic accumulation into out (poisoned before launch)
        hipMemsetAsync(out, 0, (size_t)out_size * sizeof(float), stream);
        dim3 grid(BB, SPLITS);
        masked_pool_partial_atomic<<<grid, 256, 0, stream>>>(x, mask, out);
        masked_pool_scale<<<BB, 256, 0, stream>>>(mask, out);
    }
}